// Round 7
// baseline (43.274 us; speedup 1.0000x reference)
//
#include <hip/hip_runtime.h>

#define NL 5

typedef int v2i __attribute__((ext_vector_type(2)));

// flip sign of v iff bit==1
__device__ __forceinline__ float sflip(float v, unsigned bit) {
    return __uint_as_float(__float_as_uint(v) ^ (bit << 31));
}
// new_me = c*me - i*s*other  (both halves of an RX butterfly)
__device__ __forceinline__ float2 rotg(float2 me, float ox, float oy, float c, float s) {
    return make_float2(fmaf(c, me.x,  s * oy),
                       fmaf(c, me.y, -s * ox));
}
// DPP cross-lane on the VALU pipe.
//   0xB1 = quad_perm [1,0,3,2]  -> lane^1
//   0x4E = quad_perm [2,3,0,1]  -> lane^2
//   0x1B = quad_perm [3,2,1,0]  -> lane^3
//   0x141 = row_half_mirror     -> lane^7 (within 8)
//   0x128 = row_ror:8           -> lane^8 (xor 8 within a 16-row)
template <int CTRL>
__device__ __forceinline__ float dppx(float v) {
    return __int_as_float(__builtin_amdgcn_update_dpp(
        0, __float_as_int(v), CTRL, 0xF, 0xF, true));
}
// data from lane^4 = (^7) then (^3)
__device__ __forceinline__ float dpp_x4(float v) { return dppx<0x1B>(dppx<0x141>(v)); }

// xor-16 / xor-32 exchange on the VALU pipe via gfx950 permlane*_swap.
// Feeding v to both operands: r.x = {lo,lo} halves, r.y = {hi,hi} halves
// (for MASK=32), so partner(lane^MASK) = (lane&MASK) ? r.x : r.y.
#if __has_builtin(__builtin_amdgcn_permlane32_swap) && __has_builtin(__builtin_amdgcn_permlane16_swap)
template <int MASK>
__device__ __forceinline__ float plswap(float v, bool hi) {
    v2i r;
    if (MASK == 32)
        r = __builtin_amdgcn_permlane32_swap(__float_as_int(v), __float_as_int(v), false, false);
    else
        r = __builtin_amdgcn_permlane16_swap(__float_as_int(v), __float_as_int(v), false, false);
    return __int_as_float(hi ? r.x : r.y);
}
#else
template <int MASK>
__device__ __forceinline__ float plswap(float v, bool hi) {
    return __shfl_xor(v, MASK);
}
#endif

// all-lanes butterfly sum across the 64-lane wave — entirely on the VALU pipe
__device__ __forceinline__ float wave_sum(float v, bool hi16, bool hi32) {
    v += dppx<0xB1>(v);
    v += dppx<0x4E>(v);
    v += dpp_x4(v);
    v += dppx<0x128>(v);
    v += plswap<16>(v, hi16);
    v += plswap<32>(v, hi32);
    return v;
}

__global__ __launch_bounds__(128, 4)
void ppo_quantum_kernel(const float* __restrict__ x,        // (B,55)
                        const float* __restrict__ isa,      // (5,)
                        const float* __restrict__ wa,       // (5,)
                        const float* __restrict__ osa,      // (10,)
                        const float* __restrict__ isc,      // (5,)
                        const float* __restrict__ wc,       // (5,)
                        const float* __restrict__ osc,      // (1,)
                        const int*   __restrict__ action,   // (B,)
                        float* __restrict__ out)            // (B,3)
{
    const int t    = threadIdx.x;      // 128 threads = 2 INDEPENDENT waves
    const int circ = t >> 6;           // wave 0 = actor, wave 1 = critic (same elem)
    const int lane = t & 63;
    const int elem = blockIdx.x;
    const float* __restrict__ xr = x + elem * 55;   // wave-uniform -> scalar loads

    const bool hi16 = (lane & 16) != 0;
    const bool hi32 = (lane & 32) != 0;

    // amplitude index d = (r<<6) | lane, r = 0..15
    // qubit q acts on d-bit (9-q): q0..q3 -> r bits 3..0 (register gates)
    //                              q4..q9 -> lane bits 5..0 (masks 32,16,8,4,2,1)
    unsigned lb[6];                    // lane bit of qubit 4+k
#pragma unroll
    for (int k = 0; k < 6; ++k) lb[k] = (lane >> (5 - k)) & 1u;

    // ---- expo decomposition ----
    float L = 0.f;                     // lane-only: singles 4..9 + pairs among them
#pragma unroll
    for (int k = 0; k < 6; ++k) L += sflip(xr[4 + k], lb[k]);
    {
        int p = 40;                    // J_ij for i,j in 4..9 at x[40..54]
#pragma unroll
        for (int i = 0; i < 6; ++i)
#pragma unroll
            for (int j = i + 1; j < 6; ++j)
                L += sflip(xr[p++], lb[i] ^ lb[j]);
    }
    float T0 = xr[0], T1 = xr[1], T2 = xr[2], T3 = xr[3];
#pragma unroll
    for (int k = 0; k < 6; ++k) {      // cross terms J_{i,4..9}
        T0 += sflip(xr[13 + k], lb[k]);
        T1 += sflip(xr[21 + k], lb[k]);
        T2 += sflip(xr[28 + k], lb[k]);
        T3 += sflip(xr[34 + k], lb[k]);
    }
    const float J01 = xr[10], J02 = xr[11], J03 = xr[12];
    const float J12 = xr[19], J13 = xr[20], J23 = xr[27];

    float expo[16];
#pragma unroll
    for (int r = 0; r < 16; ++r) {
        const unsigned b0 = (r >> 3) & 1u, b1 = (r >> 2) & 1u,
                       b2 = (r >> 1) & 1u, b3 = r & 1u;
        float e = L;
        e += sflip(T0, b0);       e += sflip(T1, b1);
        e += sflip(T2, b2);       e += sflip(T3, b3);
        e += sflip(J01, b0 ^ b1); e += sflip(J02, b0 ^ b2); e += sflip(J03, b0 ^ b3);
        e += sflip(J12, b1 ^ b2); e += sflip(J13, b1 ^ b3); e += sflip(J23, b2 ^ b3);
        expo[r] = e;
    }

    // ---- simulate this wave's circuit ----
    const float* iscale = circ ? isc : isa;
    const float* wts    = circ ? wc  : wa;

    float2 a[16];
#pragma unroll
    for (int r = 0; r < 16; ++r) a[r] = make_float2(0.03125f, 0.f);  // 1/sqrt(1024)

#pragma unroll 1                       // keep body inside I-cache
    for (int l = 0; l < NL; ++l) {
        const float m = -0.5f * iscale[l];
        float c, s;
        __sincosf(0.5f * wts[l], &s, &c);

        // diagonal phase
#pragma unroll
        for (int r = 0; r < 16; ++r) {
            float sn, cs;
            __sincosf(m * expo[r], &sn, &cs);
            const float re = a[r].x, im = a[r].y;
            a[r].x = fmaf(re, cs, -im * sn);
            a[r].y = fmaf(re, sn,  im * cs);
        }

        // qubits 0..3: register butterflies (r-bit masks 8,4,2,1)
#pragma unroll
        for (int g = 0; g < 4; ++g) {
            const int qm = 8 >> g;
#pragma unroll
            for (int r = 0; r < 16; ++r)
                if (!(r & qm)) {
                    const float2 lo = a[r], hi = a[r | qm];
                    a[r]      = rotg(lo, hi.x, hi.y, c, s);
                    a[r | qm] = rotg(hi, lo.x, lo.y, c, s);
                }
        }

        // qubit 4: lane^32 via permlane32_swap (VALU)
#pragma unroll
        for (int r = 0; r < 16; ++r) {
            const float ox = plswap<32>(a[r].x, hi32);
            const float oy = plswap<32>(a[r].y, hi32);
            a[r] = rotg(a[r], ox, oy, c, s);
        }
        // qubit 5: lane^16 via permlane16_swap (VALU)
#pragma unroll
        for (int r = 0; r < 16; ++r) {
            const float ox = plswap<16>(a[r].x, hi16);
            const float oy = plswap<16>(a[r].y, hi16);
            a[r] = rotg(a[r], ox, oy, c, s);
        }
        // qubit 6: lane^8 via DPP row_ror:8
#pragma unroll
        for (int r = 0; r < 16; ++r) {
            const float ox = dppx<0x128>(a[r].x);
            const float oy = dppx<0x128>(a[r].y);
            a[r] = rotg(a[r], ox, oy, c, s);
        }
        // qubit 7: lane^4 via composed DPP (^7 then ^3)
#pragma unroll
        for (int r = 0; r < 16; ++r) {
            const float ox = dpp_x4(a[r].x);
            const float oy = dpp_x4(a[r].y);
            a[r] = rotg(a[r], ox, oy, c, s);
        }
        // qubit 8: lane^2 via quad_perm
#pragma unroll
        for (int r = 0; r < 16; ++r) {
            const float ox = dppx<0x4E>(a[r].x);
            const float oy = dppx<0x4E>(a[r].y);
            a[r] = rotg(a[r], ox, oy, c, s);
        }
        // qubit 9: lane^1 via quad_perm
#pragma unroll
        for (int r = 0; r < 16; ++r) {
            const float ox = dppx<0xB1>(a[r].x);
            const float oy = dppx<0xB1>(a[r].y);
            a[r] = rotg(a[r], ox, oy, c, s);
        }
    }

    // ---- probabilities & expectation values ----
    float p[16];
#pragma unroll
    for (int r = 0; r < 16; ++r) p[r] = a[r].x * a[r].x + a[r].y * a[r].y;
    float tot = 0.f;
#pragma unroll
    for (int r = 0; r < 16; ++r) tot += p[r];

    if (circ == 0) {
        // actor: all 10 <Z_q>
        float v[10];
#pragma unroll
        for (int q = 0; q < 4; ++q) {
            const int qm = 8 >> q;
            float acc = 0.f;
#pragma unroll
            for (int r = 0; r < 16; ++r) acc += (r & qm) ? -p[r] : p[r];
            v[q] = acc;
        }
#pragma unroll
        for (int k = 0; k < 6; ++k) v[4 + k] = sflip(tot, lb[k]);
#pragma unroll
        for (int q = 0; q < 10; ++q) v[q] = wave_sum(v[q], hi16, hi32);

        // epilogue redundantly on all lanes (no divergence), lane 0 stores
        float logits[10], mx = -1e30f;
#pragma unroll
        for (int q = 0; q < 10; ++q) {
            logits[q] = v[q] * osa[q];
            mx = fmaxf(mx, logits[q]);
        }
        float se = 0.f;
#pragma unroll
        for (int q = 0; q < 10; ++q) se += __expf(logits[q] - mx);
        const float lse = __logf(se) + mx;
        float ent = 0.f;
#pragma unroll
        for (int q = 0; q < 10; ++q) {
            const float lp = logits[q] - lse;
            ent -= __expf(lp) * lp;
        }
        if (lane == 0) {
            const int act = action[elem];
            out[elem * 3 + 0] = logits[act] - lse;
            out[elem * 3 + 1] = ent;
        }
    } else {
        // critic: only <Z_0> (r-bit 3)
        float v0 = 0.f;
#pragma unroll
        for (int r = 0; r < 16; ++r) v0 += (r & 8) ? -p[r] : p[r];
        v0 = wave_sum(v0, hi16, hi32);
        if (lane == 0) out[elem * 3 + 2] = v0 * osc[0];
    }
}

extern "C" void kernel_launch(void* const* d_in, const int* in_sizes, int n_in,
                              void* d_out, int out_size, void* d_ws, size_t ws_size,
                              hipStream_t stream) {
    const float* x      = (const float*)d_in[0];
    const float* isa    = (const float*)d_in[1];
    const float* wa     = (const float*)d_in[2];
    const float* osa    = (const float*)d_in[3];
    const float* isc    = (const float*)d_in[4];
    const float* wc     = (const float*)d_in[5];
    const float* osc    = (const float*)d_in[6];
    const int*   action = (const int*)d_in[7];
    float*       out    = (float*)d_out;

    const int B = in_sizes[7];
    // one block per element: wave 0 = actor, wave 1 = critic; no barriers, no LDS, no DS
    ppo_quantum_kernel<<<B, 128, 0, stream>>>(x, isa, wa, osa, isc, wc, osc,
                                              action, out);
}

// Round 8
// 35.497 us; speedup vs baseline: 1.2191x; 1.2191x over previous
//
#include <hip/hip_runtime.h>

#define NL 5

typedef float v2f __attribute__((ext_vector_type(2)));

// flip sign of v iff bit==1
__device__ __forceinline__ float sflip(float v, unsigned bit) {
    return __uint_as_float(__float_as_uint(v) ^ (bit << 31));
}

// ---- packed FP32 complex helpers (VOP3P, 2 FLOP/lane/instr) ----
// RX butterfly: new = (c*me.x + s*o.y, c*me.y - s*o.x), sc = (s, c)
__device__ __forceinline__ v2f rotg_pk(v2f me, v2f o, v2f sc) {
    v2f t, r;
    // t.lo = s*o.hi ; t.hi = -s*o.lo
    asm("v_pk_mul_f32 %0, %1, %2 op_sel:[0,1] op_sel_hi:[0,0] neg_hi:[1,0]"
        : "=v"(t) : "v"(sc), "v"(o));
    // r.lo = c*me.lo + t.lo ; r.hi = c*me.hi + t.hi
    asm("v_pk_fma_f32 %0, %1, %2, %3 op_sel:[1,0,0] op_sel_hi:[1,1,1]"
        : "=v"(r) : "v"(sc), "v"(me), "v"(t));
    return r;
}
// complex phase: new = (x*cs - y*sn, x*sn + y*cs), sc = (sn, cs)
__device__ __forceinline__ v2f cmul_pk(v2f a, v2f sc) {
    v2f t, r;
    // t.lo = -sn*a.hi ; t.hi = sn*a.lo
    asm("v_pk_mul_f32 %0, %1, %2 op_sel:[0,1] op_sel_hi:[0,0] neg_lo:[1,0]"
        : "=v"(t) : "v"(sc), "v"(a));
    // r.lo = cs*a.lo + t.lo ; r.hi = cs*a.hi + t.hi
    asm("v_pk_fma_f32 %0, %1, %2, %3 op_sel:[1,0,0] op_sel_hi:[1,1,1]"
        : "=v"(r) : "v"(sc), "v"(a), "v"(t));
    return r;
}

// DPP cross-lane on the VALU pipe.
//   0xB1 = quad_perm [1,0,3,2]  -> lane^1
//   0x4E = quad_perm [2,3,0,1]  -> lane^2
//   0x1B = quad_perm [3,2,1,0]  -> lane^3
//   0x141 = row_half_mirror     -> lane^7 (within 8)
//   0x128 = row_ror:8           -> lane^8 (xor 8 within a 16-row)
template <int CTRL>
__device__ __forceinline__ float dppx(float v) {
    return __int_as_float(__builtin_amdgcn_update_dpp(
        0, __float_as_int(v), CTRL, 0xF, 0xF, true));
}
// data from lane^4 = (^7) then (^3)
__device__ __forceinline__ float dpp_x4(float v) { return dppx<0x1B>(dppx<0x141>(v)); }

// all-lanes butterfly sum across the 64-lane wave
__device__ __forceinline__ float wave_sum(float v) {
    v += dppx<0xB1>(v);
    v += dppx<0x4E>(v);
    v += dpp_x4(v);
    v += dppx<0x128>(v);
    v += __shfl_xor(v, 16);
    v += __shfl_xor(v, 32);
    return v;
}

__global__ __launch_bounds__(128, 4)
void ppo_quantum_kernel(const float* __restrict__ x,        // (B,55)
                        const float* __restrict__ isa,      // (5,)
                        const float* __restrict__ wa,       // (5,)
                        const float* __restrict__ osa,      // (10,)
                        const float* __restrict__ isc,      // (5,)
                        const float* __restrict__ wc,       // (5,)
                        const float* __restrict__ osc,      // (1,)
                        const int*   __restrict__ action,   // (B,)
                        float* __restrict__ out)            // (B,3)
{
    const int t    = threadIdx.x;      // 128 threads = 2 INDEPENDENT waves
    const int circ = t >> 6;           // wave 0 = actor, wave 1 = critic (same elem)
    const int lane = t & 63;
    const int elem = blockIdx.x;
    const float* __restrict__ xr = x + elem * 55;   // wave-uniform -> scalar loads

    // amplitude index d = (r<<6) | lane, r = 0..15
    // qubit q acts on d-bit (9-q): q0..q3 -> r bits 3..0 (register gates)
    //                              q4..q9 -> lane bits 5..0 (masks 32,16,8,4,2,1)
    unsigned lb[6];                    // lane bit of qubit 4+k
#pragma unroll
    for (int k = 0; k < 6; ++k) lb[k] = (lane >> (5 - k)) & 1u;

    // ---- expo decomposition ----
    float L = 0.f;                     // lane-only: singles 4..9 + pairs among them
#pragma unroll
    for (int k = 0; k < 6; ++k) L += sflip(xr[4 + k], lb[k]);
    {
        int p = 40;                    // J_ij for i,j in 4..9 at x[40..54]
#pragma unroll
        for (int i = 0; i < 6; ++i)
#pragma unroll
            for (int j = i + 1; j < 6; ++j)
                L += sflip(xr[p++], lb[i] ^ lb[j]);
    }
    float T0 = xr[0], T1 = xr[1], T2 = xr[2], T3 = xr[3];
#pragma unroll
    for (int k = 0; k < 6; ++k) {      // cross terms J_{i,4..9}
        T0 += sflip(xr[13 + k], lb[k]);
        T1 += sflip(xr[21 + k], lb[k]);
        T2 += sflip(xr[28 + k], lb[k]);
        T3 += sflip(xr[34 + k], lb[k]);
    }
    const float J01 = xr[10], J02 = xr[11], J03 = xr[12];
    const float J12 = xr[19], J13 = xr[20], J23 = xr[27];

    float expo[16];
#pragma unroll
    for (int r = 0; r < 16; ++r) {
        const unsigned b0 = (r >> 3) & 1u, b1 = (r >> 2) & 1u,
                       b2 = (r >> 1) & 1u, b3 = r & 1u;
        float e = L;
        e += sflip(T0, b0);       e += sflip(T1, b1);
        e += sflip(T2, b2);       e += sflip(T3, b3);
        e += sflip(J01, b0 ^ b1); e += sflip(J02, b0 ^ b2); e += sflip(J03, b0 ^ b3);
        e += sflip(J12, b1 ^ b2); e += sflip(J13, b1 ^ b3); e += sflip(J23, b2 ^ b3);
        expo[r] = e;
    }

    // ---- simulate this wave's circuit ----
    const float* iscale = circ ? isc : isa;
    const float* wts    = circ ? wc  : wa;

    v2f a[16];
#pragma unroll
    for (int r = 0; r < 16; ++r) a[r] = (v2f){0.03125f, 0.f};  // 1/sqrt(1024)

#pragma unroll 1                       // keep body inside I-cache
    for (int l = 0; l < NL; ++l) {
        const float m = -0.5f * iscale[l];
        float c, s;
        __sincosf(0.5f * wts[l], &s, &c);
        const v2f sc = {s, c};

        // diagonal phase (packed complex mul)
#pragma unroll
        for (int r = 0; r < 16; ++r) {
            float sn, cs;
            __sincosf(m * expo[r], &sn, &cs);
            const v2f ph = {sn, cs};
            a[r] = cmul_pk(a[r], ph);
        }

        // qubits 0..3: register butterflies (r-bit masks 8,4,2,1)
#pragma unroll
        for (int g = 0; g < 4; ++g) {
            const int qm = 8 >> g;
#pragma unroll
            for (int r = 0; r < 16; ++r)
                if (!(r & qm)) {
                    const v2f lo = a[r], hi = a[r | qm];
                    a[r]      = rotg_pk(lo, hi, sc);
                    a[r | qm] = rotg_pk(hi, lo, sc);
                }
        }

        // qubit 4: lane^32 (ds_swizzle)
#pragma unroll
        for (int r = 0; r < 16; ++r) {
            const v2f o = {__shfl_xor(a[r].x, 32), __shfl_xor(a[r].y, 32)};
            a[r] = rotg_pk(a[r], o, sc);
        }
        // qubit 5: lane^16 (ds_swizzle)
#pragma unroll
        for (int r = 0; r < 16; ++r) {
            const v2f o = {__shfl_xor(a[r].x, 16), __shfl_xor(a[r].y, 16)};
            a[r] = rotg_pk(a[r], o, sc);
        }
        // qubit 6: lane^8 via DPP row_ror:8
#pragma unroll
        for (int r = 0; r < 16; ++r) {
            const v2f o = {dppx<0x128>(a[r].x), dppx<0x128>(a[r].y)};
            a[r] = rotg_pk(a[r], o, sc);
        }
        // qubit 7: lane^4 via composed DPP (^7 then ^3)
#pragma unroll
        for (int r = 0; r < 16; ++r) {
            const v2f o = {dpp_x4(a[r].x), dpp_x4(a[r].y)};
            a[r] = rotg_pk(a[r], o, sc);
        }
        // qubit 8: lane^2 via quad_perm
#pragma unroll
        for (int r = 0; r < 16; ++r) {
            const v2f o = {dppx<0x4E>(a[r].x), dppx<0x4E>(a[r].y)};
            a[r] = rotg_pk(a[r], o, sc);
        }
        // qubit 9: lane^1 via quad_perm
#pragma unroll
        for (int r = 0; r < 16; ++r) {
            const v2f o = {dppx<0xB1>(a[r].x), dppx<0xB1>(a[r].y)};
            a[r] = rotg_pk(a[r], o, sc);
        }
    }

    // ---- probabilities & expectation values ----
    float p[16];
#pragma unroll
    for (int r = 0; r < 16; ++r) p[r] = a[r].x * a[r].x + a[r].y * a[r].y;
    float tot = 0.f;
#pragma unroll
    for (int r = 0; r < 16; ++r) tot += p[r];

    if (circ == 0) {
        // actor: all 10 <Z_q>
        float v[10];
#pragma unroll
        for (int q = 0; q < 4; ++q) {
            const int qm = 8 >> q;
            float acc = 0.f;
#pragma unroll
            for (int r = 0; r < 16; ++r) acc += (r & qm) ? -p[r] : p[r];
            v[q] = acc;
        }
#pragma unroll
        for (int k = 0; k < 6; ++k) v[4 + k] = sflip(tot, lb[k]);
#pragma unroll
        for (int q = 0; q < 10; ++q) v[q] = wave_sum(v[q]);

        // epilogue redundantly on all lanes (no divergence), lane 0 stores
        float logits[10], mx = -1e30f;
#pragma unroll
        for (int q = 0; q < 10; ++q) {
            logits[q] = v[q] * osa[q];
            mx = fmaxf(mx, logits[q]);
        }
        float se = 0.f;
#pragma unroll
        for (int q = 0; q < 10; ++q) se += __expf(logits[q] - mx);
        const float lse = __logf(se) + mx;
        float ent = 0.f;
#pragma unroll
        for (int q = 0; q < 10; ++q) {
            const float lp = logits[q] - lse;
            ent -= __expf(lp) * lp;
        }
        if (lane == 0) {
            const int act = action[elem];
            out[elem * 3 + 0] = logits[act] - lse;
            out[elem * 3 + 1] = ent;
        }
    } else {
        // critic: only <Z_0> (r-bit 3)
        float v0 = 0.f;
#pragma unroll
        for (int r = 0; r < 16; ++r) v0 += (r & 8) ? -p[r] : p[r];
        v0 = wave_sum(v0);
        if (lane == 0) out[elem * 3 + 2] = v0 * osc[0];
    }
}

extern "C" void kernel_launch(void* const* d_in, const int* in_sizes, int n_in,
                              void* d_out, int out_size, void* d_ws, size_t ws_size,
                              hipStream_t stream) {
    const float* x      = (const float*)d_in[0];
    const float* isa    = (const float*)d_in[1];
    const float* wa     = (const float*)d_in[2];
    const float* osa    = (const float*)d_in[3];
    const float* isc    = (const float*)d_in[4];
    const float* wc     = (const float*)d_in[5];
    const float* osc    = (const float*)d_in[6];
    const int*   action = (const int*)d_in[7];
    float*       out    = (float*)d_out;

    const int B = in_sizes[7];
    // one block per element: wave 0 = actor, wave 1 = critic; no barriers, no LDS
    ppo_quantum_kernel<<<B, 128, 0, stream>>>(x, isa, wa, osa, isc, wc, osc,
                                              action, out);
}

// Round 11
// 35.487 us; speedup vs baseline: 1.2194x; 1.0003x over previous
//
#include <hip/hip_runtime.h>

#define NL 5

typedef float v2f __attribute__((ext_vector_type(2)));

// flip sign of v iff bit==1
__device__ __forceinline__ float sflip(float v, unsigned bit) {
    return __uint_as_float(__float_as_uint(v) ^ (bit << 31));
}

// ---- packed FP32 complex helpers (VOP3P, 2 FLOP/lane/instr) ----
// RX butterfly: new = (c*me.x + s*o.y, c*me.y - s*o.x), sc = (s, c)
__device__ __forceinline__ v2f rotg_pk(v2f me, v2f o, v2f sc) {
    v2f t, r;
    // t.lo = s*o.hi ; t.hi = -s*o.lo
    asm("v_pk_mul_f32 %0, %1, %2 op_sel:[0,1] op_sel_hi:[0,0] neg_hi:[1,0]"
        : "=v"(t) : "v"(sc), "v"(o));
    // r.lo = c*me.lo + t.lo ; r.hi = c*me.hi + t.hi
    asm("v_pk_fma_f32 %0, %1, %2, %3 op_sel:[1,0,0] op_sel_hi:[1,1,1]"
        : "=v"(r) : "v"(sc), "v"(me), "v"(t));
    return r;
}
// complex phase: new = (x*cs - y*sn, x*sn + y*cs), sc = (sn, cs)
__device__ __forceinline__ v2f cmul_pk(v2f a, v2f sc) {
    v2f t, r;
    // t.lo = -sn*a.hi ; t.hi = sn*a.lo
    asm("v_pk_mul_f32 %0, %1, %2 op_sel:[0,1] op_sel_hi:[0,0] neg_lo:[1,0]"
        : "=v"(t) : "v"(sc), "v"(a));
    // r.lo = cs*a.lo + t.lo ; r.hi = cs*a.hi + t.hi
    asm("v_pk_fma_f32 %0, %1, %2, %3 op_sel:[1,0,0] op_sel_hi:[1,1,1]"
        : "=v"(r) : "v"(sc), "v"(a), "v"(t));
    return r;
}

// DPP cross-lane on the VALU pipe.
//   0xB1 = quad_perm [1,0,3,2]  -> lane^1
//   0x4E = quad_perm [2,3,0,1]  -> lane^2
//   0x1B = quad_perm [3,2,1,0]  -> lane^3
//   0x141 = row_half_mirror     -> lane^7 (within 8)
//   0x128 = row_ror:8           -> lane^8 (xor 8 within a 16-row)
template <int CTRL>
__device__ __forceinline__ float dppx(float v) {
    return __int_as_float(__builtin_amdgcn_update_dpp(
        0, __float_as_int(v), CTRL, 0xF, 0xF, true));
}
// data from lane^4 = (^7) then (^3)
__device__ __forceinline__ float dpp_x4(float v) { return dppx<0x1B>(dppx<0x141>(v)); }

// ---- permlane pair-swap (inline asm, "+v" tied in/out) ----
// v_permlane32_swap_b32 vdst,vsrc: swaps vdst's upper 32 lanes with vsrc's
// lower 32 lanes. v_permlane16_swap_b32: swaps odd 16-rows of vdst with even
// 16-rows of vsrc. After the swap each lane holds both xor-MASK partners of
// one logical register -> butterfly is lane-local; swap again to restore.
template <bool IS32>
__device__ __forceinline__ void swap_pair(float &X, float &Y) {
    if (IS32)
        asm("v_permlane32_swap_b32 %0, %1" : "+v"(X), "+v"(Y));
    else
        asm("v_permlane16_swap_b32 %0, %1" : "+v"(X), "+v"(Y));
}
// RX gate for lane-mask 32 (IS32) or 16 on a register pair (A,B): swap in,
// lane-local butterfly (the 2 rotg_pk we'd do anyway), swap back.
template <bool IS32>
__device__ __forceinline__ void gate_pl(v2f &A, v2f &B, v2f sc) {
    float ax = A.x, ay = A.y, bx = B.x, by = B.y;
    swap_pair<IS32>(ax, bx);
    swap_pair<IS32>(ay, by);
    const v2f u = {ax, ay}, v = {bx, by};
    v2f nu = rotg_pk(u, v, sc);
    v2f nv = rotg_pk(v, u, sc);
    ax = nu.x; ay = nu.y; bx = nv.x; by = nv.y;
    swap_pair<IS32>(ax, bx);
    swap_pair<IS32>(ay, by);
    A = (v2f){ax, ay};
    B = (v2f){bx, by};
}

// all-lanes butterfly sum across the 64-lane wave (one-shot, DS ok)
__device__ __forceinline__ float wave_sum(float v) {
    v += dppx<0xB1>(v);
    v += dppx<0x4E>(v);
    v += dpp_x4(v);
    v += dppx<0x128>(v);
    v += __shfl_xor(v, 16);
    v += __shfl_xor(v, 32);
    return v;
}

__global__ __launch_bounds__(128, 4)
void ppo_quantum_kernel(const float* __restrict__ x,        // (B,55)
                        const float* __restrict__ isa,      // (5,)
                        const float* __restrict__ wa,       // (5,)
                        const float* __restrict__ osa,      // (10,)
                        const float* __restrict__ isc,      // (5,)
                        const float* __restrict__ wc,       // (5,)
                        const float* __restrict__ osc,      // (1,)
                        const int*   __restrict__ action,   // (B,)
                        float* __restrict__ out)            // (B,3)
{
    const int t    = threadIdx.x;      // 128 threads = 2 INDEPENDENT waves
    const int circ = t >> 6;           // wave 0 = actor, wave 1 = critic (same elem)
    const int lane = t & 63;
    const int elem = blockIdx.x;
    const float* __restrict__ xr = x + elem * 55;   // wave-uniform -> scalar loads

    // amplitude index d = (r<<6) | lane, r = 0..15
    // qubit q acts on d-bit (9-q): q0..q3 -> r bits 3..0 (register gates)
    //                              q4..q9 -> lane bits 5..0 (masks 32,16,8,4,2,1)
    unsigned lb[6];                    // lane bit of qubit 4+k
#pragma unroll
    for (int k = 0; k < 6; ++k) lb[k] = (lane >> (5 - k)) & 1u;

    // ---- expo decomposition ----
    float L = 0.f;                     // lane-only: singles 4..9 + pairs among them
#pragma unroll
    for (int k = 0; k < 6; ++k) L += sflip(xr[4 + k], lb[k]);
    {
        int p = 40;                    // J_ij for i,j in 4..9 at x[40..54]
#pragma unroll
        for (int i = 0; i < 6; ++i)
#pragma unroll
            for (int j = i + 1; j < 6; ++j)
                L += sflip(xr[p++], lb[i] ^ lb[j]);
    }
    float T0 = xr[0], T1 = xr[1], T2 = xr[2], T3 = xr[3];
#pragma unroll
    for (int k = 0; k < 6; ++k) {      // cross terms J_{i,4..9}
        T0 += sflip(xr[13 + k], lb[k]);
        T1 += sflip(xr[21 + k], lb[k]);
        T2 += sflip(xr[28 + k], lb[k]);
        T3 += sflip(xr[34 + k], lb[k]);
    }
    const float J01 = xr[10], J02 = xr[11], J03 = xr[12];
    const float J12 = xr[19], J13 = xr[20], J23 = xr[27];

    float expo[16];
#pragma unroll
    for (int r = 0; r < 16; ++r) {
        const unsigned b0 = (r >> 3) & 1u, b1 = (r >> 2) & 1u,
                       b2 = (r >> 1) & 1u, b3 = r & 1u;
        float e = L;
        e += sflip(T0, b0);       e += sflip(T1, b1);
        e += sflip(T2, b2);       e += sflip(T3, b3);
        e += sflip(J01, b0 ^ b1); e += sflip(J02, b0 ^ b2); e += sflip(J03, b0 ^ b3);
        e += sflip(J12, b1 ^ b2); e += sflip(J13, b1 ^ b3); e += sflip(J23, b2 ^ b3);
        expo[r] = e;
    }

    // ---- simulate this wave's circuit ----
    const float* iscale = circ ? isc : isa;
    const float* wts    = circ ? wc  : wa;

    v2f a[16];
#pragma unroll
    for (int r = 0; r < 16; ++r) a[r] = (v2f){0.03125f, 0.f};  // 1/sqrt(1024)

#pragma unroll 1                       // keep body inside I-cache
    for (int l = 0; l < NL; ++l) {
        const float m = -0.5f * iscale[l];
        float c, s;
        __sincosf(0.5f * wts[l], &s, &c);
        const v2f sc = {s, c};

        // diagonal phase (packed complex mul)
#pragma unroll
        for (int r = 0; r < 16; ++r) {
            float sn, cs;
            __sincosf(m * expo[r], &sn, &cs);
            const v2f ph = {sn, cs};
            a[r] = cmul_pk(a[r], ph);
        }

        // qubits 0..3: register butterflies (r-bit masks 8,4,2,1)
#pragma unroll
        for (int g = 0; g < 4; ++g) {
            const int qm = 8 >> g;
#pragma unroll
            for (int r = 0; r < 16; ++r)
                if (!(r & qm)) {
                    const v2f lo = a[r], hi = a[r | qm];
                    a[r]      = rotg_pk(lo, hi, sc);
                    a[r | qm] = rotg_pk(hi, lo, sc);
                }
        }

        // qubit 4: lane^32 via paired permlane32_swap (VALU, no DS)
#pragma unroll
        for (int r = 0; r < 16; r += 2) gate_pl<true>(a[r], a[r + 1], sc);
        // qubit 5: lane^16 via paired permlane16_swap (VALU, no DS)
#pragma unroll
        for (int r = 0; r < 16; r += 2) gate_pl<false>(a[r], a[r + 1], sc);

        // qubit 6: lane^8 via DPP row_ror:8
#pragma unroll
        for (int r = 0; r < 16; ++r) {
            const v2f o = {dppx<0x128>(a[r].x), dppx<0x128>(a[r].y)};
            a[r] = rotg_pk(a[r], o, sc);
        }
        // qubit 7: lane^4 via composed DPP (^7 then ^3)
#pragma unroll
        for (int r = 0; r < 16; ++r) {
            const v2f o = {dpp_x4(a[r].x), dpp_x4(a[r].y)};
            a[r] = rotg_pk(a[r], o, sc);
        }
        // qubit 8: lane^2 via quad_perm
#pragma unroll
        for (int r = 0; r < 16; ++r) {
            const v2f o = {dppx<0x4E>(a[r].x), dppx<0x4E>(a[r].y)};
            a[r] = rotg_pk(a[r], o, sc);
        }
        // qubit 9: lane^1 via quad_perm
#pragma unroll
        for (int r = 0; r < 16; ++r) {
            const v2f o = {dppx<0xB1>(a[r].x), dppx<0xB1>(a[r].y)};
            a[r] = rotg_pk(a[r], o, sc);
        }
    }

    // ---- probabilities & expectation values ----
    float p[16];
#pragma unroll
    for (int r = 0; r < 16; ++r) p[r] = a[r].x * a[r].x + a[r].y * a[r].y;
    float tot = 0.f;
#pragma unroll
    for (int r = 0; r < 16; ++r) tot += p[r];

    if (circ == 0) {
        // actor: all 10 <Z_q>
        float v[10];
#pragma unroll
        for (int q = 0; q < 4; ++q) {
            const int qm = 8 >> q;
            float acc = 0.f;
#pragma unroll
            for (int r = 0; r < 16; ++r) acc += (r & qm) ? -p[r] : p[r];
            v[q] = acc;
        }
#pragma unroll
        for (int k = 0; k < 6; ++k) v[4 + k] = sflip(tot, lb[k]);
#pragma unroll
        for (int q = 0; q < 10; ++q) v[q] = wave_sum(v[q]);

        // epilogue redundantly on all lanes (no divergence), lane 0 stores
        float logits[10], mx = -1e30f;
#pragma unroll
        for (int q = 0; q < 10; ++q) {
            logits[q] = v[q] * osa[q];
            mx = fmaxf(mx, logits[q]);
        }
        float se = 0.f;
#pragma unroll
        for (int q = 0; q < 10; ++q) se += __expf(logits[q] - mx);
        const float lse = __logf(se) + mx;
        float ent = 0.f;
#pragma unroll
        for (int q = 0; q < 10; ++q) {
            const float lp = logits[q] - lse;
            ent -= __expf(lp) * lp;
        }
        if (lane == 0) {
            const int act = action[elem];
            out[elem * 3 + 0] = logits[act] - lse;
            out[elem * 3 + 1] = ent;
        }
    } else {
        // critic: only <Z_0> (r-bit 3)
        float v0 = 0.f;
#pragma unroll
        for (int r = 0; r < 16; ++r) v0 += (r & 8) ? -p[r] : p[r];
        v0 = wave_sum(v0);
        if (lane == 0) out[elem * 3 + 2] = v0 * osc[0];
    }
}

extern "C" void kernel_launch(void* const* d_in, const int* in_sizes, int n_in,
                              void* d_out, int out_size, void* d_ws, size_t ws_size,
                              hipStream_t stream) {
    const float* x      = (const float*)d_in[0];
    const float* isa    = (const float*)d_in[1];
    const float* wa     = (const float*)d_in[2];
    const float* osa    = (const float*)d_in[3];
    const float* isc    = (const float*)d_in[4];
    const float* wc     = (const float*)d_in[5];
    const float* osc    = (const float*)d_in[6];
    const int*   action = (const int*)d_in[7];
    float*       out    = (float*)d_out;

    const int B = in_sizes[7];
    // one block per element: wave 0 = actor, wave 1 = critic; no barriers, no LDS
    ppo_quantum_kernel<<<B, 128, 0, stream>>>(x, isa, wa, osa, isc, wc, osc,
                                              action, out);
}